// Round 4
// baseline (427.478 us; speedup 1.0000x reference)
//
#include <hip/hip_runtime.h>
#include <stdint.h>
#include <stddef.h>

typedef int i32x4 __attribute__((ext_vector_type(4)));

static constexpr int M = 8192, N = 4096, K = 4096;
static constexpr int BM = 256, BN = 256, BK = 128;  // 256^2 tile, 2 k-half units of 64B
static constexpr int NT = K / BK;                   // 32 K-tiles

// ---------------- fused preprocessing ----------------
// blocks [0, M): per-row absmax-quant of x -> xq, scales
// blocks [M, M + N*K/1024): binarize w -> wq
// Fusing lets the two independent memory-bound jobs run concurrently.

__global__ __launch_bounds__(256) void prep(const float* __restrict__ x,
                                            const float* __restrict__ w,
                                            int8_t* __restrict__ xq,
                                            float* __restrict__ scales,
                                            int8_t* __restrict__ wq) {
    __shared__ float wm[4];
    const int tid = threadIdx.x;

    if (blockIdx.x < M) {
        const int row = blockIdx.x;
        const float4* xr = (const float4*)(x + (size_t)row * K);  // 1024 float4/row

        float4 v[4];
        float m = 0.f;
#pragma unroll
        for (int k = 0; k < 4; ++k) {
            v[k] = xr[k * 256 + tid];
            m = fmaxf(m, fmaxf(fmaxf(fabsf(v[k].x), fabsf(v[k].y)),
                               fmaxf(fabsf(v[k].z), fabsf(v[k].w))));
        }
#pragma unroll
        for (int off = 32; off; off >>= 1) m = fmaxf(m, __shfl_down(m, off, 64));

        if ((tid & 63) == 0) wm[tid >> 6] = m;
        __syncthreads();
        const float amax = fmaxf(fmaxf(fmaxf(wm[0], wm[1]), fmaxf(wm[2], wm[3])), 1e-20f);
        const float s = 127.0f / amax;
        if (tid == 0) scales[row] = amax * (1.0f / 127.0f);

        int8_t* xo = xq + (size_t)row * K;
#pragma unroll
        for (int k = 0; k < 4; ++k) {
            int8_t o[4] = {(int8_t)__float2int_rn(v[k].x * s),
                           (int8_t)__float2int_rn(v[k].y * s),
                           (int8_t)__float2int_rn(v[k].z * s),
                           (int8_t)__float2int_rn(v[k].w * s)};
            *(int*)(xo + (k * 256 + tid) * 4) = *(const int*)o;
        }
    } else {
        const size_t i = (size_t)(blockIdx.x - M) * 256 + tid;
        float4 a = ((const float4*)w)[i];
        float vv[4] = {a.x, a.y, a.z, a.w};
        int8_t o[4];
#pragma unroll
        for (int j = 0; j < 4; ++j)
            o[j] = (vv[j] > 0.f) ? (int8_t)1 : ((vv[j] < 0.f) ? (int8_t)-1 : (int8_t)0);
        *(int*)(wq + 4 * i) = *(const int*)o;
    }
}

// ---------------- GEMM: 256^2 tile, 4 fine phases / K-tile, counted vmcnt ----------------
// C[M,N] = (Xq[M,K] @ Wq[N,K]^T) * scales[row] + bias[col]
// 512 threads = 8 waves (2 rows x 4 cols), per-wave output 128x64.
// LDS: per matrix 2 buffers x 2 k-half units of [256 rows x 64 B] = 64 KB; total 128 KB.
// Swizzle f(r) = (r>>1)&3 (conflict-free, verified R2/R3: 0 bank conflicts).
// R4 CHANGE: m201's fine-phase interleave. R3's coarse phases (12 reads | bar | 32 MFMA)
//   measured fully SERIAL pipes: 2960 cyc/phase = reads(1152) + MFMA(1306) + sync — the
//   LDS pipe idles during the MFMA drain and vice versa (MFMA issue back-pressures, so a
//   wave reaches the barrier only after its whole cluster issued). m196/m201: the fine
//   per-phase interleave (~8 reads + 16 MFMA) is what creates wave stagger -> pipe overlap.
// Per K-tile t, 4 phases (ks x mi-half), each: {reads; stage 2 loads; bar; 16 MFMA
//   (setprio); [counted wait]; bar}:
//   p0: bf0[0-3]+af0[0-3] reads; stage A-half of (t+1,k1); 16 MFMA mi0-3 ks0
//   p1: af0[4-7] reads;         stage B-half of (t+1,k1); 16 MFMA mi4-7 ks0; WAITVM(8)
//   p2: bf1[0-3]+af1[0-3];      stage A-half of (t+2,k0); 16 MFMA mi0-3 ks1
//   p3: af1[4-7];               stage B-half of (t+2,k0); 16 MFMA mi4-7 ks1; WAITVM(8)
// Ledger (2-op groups, newest-first at each wait; verified steady + prologue + tail):
//   end-p1 needs (t,k1) [staged p0-p1 of t-1]  -> newest 8 in flight -> WAITVM(8)
//   end-p3 needs (t+1,k0) [staged p2-p3 of t-1] -> newest 8 in flight -> WAITVM(8)
//   tail: t=NT-2: p1->8, p3->4; t=NT-1: p1->0, p3->skip.

__device__ __forceinline__ void async_copy16(const int8_t* g, int8_t* l) {
    __builtin_amdgcn_global_load_lds(
        (const __attribute__((address_space(1))) void*)g,
        (__attribute__((address_space(3))) void*)l,
        16, 0, 0);
}

#define SFENCE() __builtin_amdgcn_sched_barrier(0)
#define BAR() __builtin_amdgcn_s_barrier()
#define WAITVM(NN) asm volatile("s_waitcnt vmcnt(" #NN ")")

__global__ __launch_bounds__(512, 2) void gemm_i8(const int8_t* __restrict__ A,   // [M,K]
                                                  const int8_t* __restrict__ B,   // [N,K]
                                                  const float* __restrict__ bias,
                                                  const float* __restrict__ scales,
                                                  float* __restrict__ C) {        // [M,N]
    __shared__ __align__(16) int8_t As[2][2][BM * 64];  // 64 KB
    __shared__ __align__(16) int8_t Bs[2][2][BN * 64];  // 64 KB

    const int tid  = threadIdx.x;
    const int lane = tid & 63;
    const int wave = tid >> 6;
    const int wr = wave >> 2;       // 0..1  (row half of tile)
    const int wc = wave & 3;        // 0..3  (col quarter)
    const int q  = lane >> 4;       // k-chunk within 64-wide k-step
    const int lr = lane & 15;

    // XCD swizzle (m-fast within chunk, as measured in R3)
    const int wg  = blockIdx.x;
    const int swz = (wg & 7) * 64 + (wg >> 3);
    const int m0  = (swz & 31) * BM;   // 32 m-tiles, fast
    const int n0  = (swz >> 5) * BN;   // 16 n-tiles, slow

    i32x4 acc[8][4];
#pragma unroll
    for (int mi = 0; mi < 8; ++mi)
#pragma unroll
        for (int ni = 0; ni < 4; ++ni) acc[mi][ni] = (i32x4)0;

    // fragment LDS byte offsets within a 16 KB unit; granule = q ^ ((r>>1)&3)
    int aoff[8], boff[4];
#pragma unroll
    for (int mi = 0; mi < 8; ++mi) {
        const int r = wr * 128 + mi * 16 + lr;
        aoff[mi] = r * 64 + ((q ^ ((r >> 1) & 3)) * 16);
    }
#pragma unroll
    for (int ni = 0; ni < 4; ++ni) {
        const int r = wc * 64 + ni * 16 + lr;
        boff[ni] = r * 64 + ((q ^ ((r >> 1) & 3)) * 16);
    }

    // staging: slot s -> row r=s>>2, lds-granule c=s&3, source granule (s&3)^((s>>3)&3).
    // LDS dest linear (wave base + lane*16) -> staging writes conflict-free.
    const int s0 = tid, s1 = tid + 512;
    const int8_t* sA0 = A + (size_t)(m0 + (s0 >> 2)) * K + (((s0 & 3) ^ ((s0 >> 3) & 3)) * 16);
    const int8_t* sA1 = A + (size_t)(m0 + (s1 >> 2)) * K + (((s1 & 3) ^ ((s1 >> 3) & 3)) * 16);
    const int8_t* sB0 = B + (size_t)(n0 + (s0 >> 2)) * K + (((s0 & 3) ^ ((s0 >> 3) & 3)) * 16);
    const int8_t* sB1 = B + (size_t)(n0 + (s1 >> 2)) * K + (((s1 & 3) ^ ((s1 >> 3) & 3)) * 16);

#define STAGE_A(buf, kh, kt) do {                                  \
        const int _ko = (kt) * BK + (kh) * 64;                     \
        async_copy16(sA0 + _ko, &As[buf][kh][s0 * 16]);            \
        async_copy16(sA1 + _ko, &As[buf][kh][s1 * 16]);            \
    } while (0)
#define STAGE_B(buf, kh, kt) do {                                  \
        const int _ko = (kt) * BK + (kh) * 64;                     \
        async_copy16(sB0 + _ko, &Bs[buf][kh][s0 * 16]);            \
        async_copy16(sB1 + _ko, &Bs[buf][kh][s1 * 16]);            \
    } while (0)

    // prologue: (0,k0), (0,k1), (1,k0) issued (12 ops); retire first unit; 8 stay in flight
    STAGE_A(0, 0, 0); STAGE_B(0, 0, 0);
    STAGE_A(0, 1, 0); STAGE_B(0, 1, 0);
    STAGE_A(1, 0, 1); STAGE_B(1, 0, 1);
    SFENCE();
    WAITVM(8);
    SFENCE();
    BAR();
    SFENCE();

    for (int t = 0; t < NT; ++t) {
        const int cur = t & 1;
        const int nxt = cur ^ 1;

#pragma unroll
        for (int ks = 0; ks < 2; ++ks) {
            const int8_t* Au = &As[cur][ks][0];
            const int8_t* Bu = &Bs[cur][ks][0];
            i32x4 bf[4], af[4];

            // ---- phase (ks,0): mi 0-3 ----
#pragma unroll
            for (int ni = 0; ni < 4; ++ni) bf[ni] = *(const i32x4*)(Bu + boff[ni]);
#pragma unroll
            for (int mi = 0; mi < 4; ++mi) af[mi] = *(const i32x4*)(Au + aoff[mi]);
            if (ks == 0) { if (t + 1 < NT) STAGE_A(nxt, 1, t + 1); }
            else         { if (t + 2 < NT) STAGE_A(cur, 0, t + 2); }
            SFENCE();
            BAR();
            SFENCE();
            __builtin_amdgcn_s_setprio(1);
#pragma unroll
            for (int mi = 0; mi < 4; ++mi)
#pragma unroll
                for (int ni = 0; ni < 4; ++ni)
                    acc[mi][ni] = __builtin_amdgcn_mfma_i32_16x16x64_i8(
                        af[mi], bf[ni], acc[mi][ni], 0, 0, 0);
            __builtin_amdgcn_s_setprio(0);
            SFENCE();
            BAR();
            SFENCE();

            // ---- phase (ks,1): mi 4-7 ----
#pragma unroll
            for (int mi = 0; mi < 4; ++mi) af[mi] = *(const i32x4*)(Au + aoff[mi + 4]);
            if (ks == 0) { if (t + 1 < NT) STAGE_B(nxt, 1, t + 1); }
            else         { if (t + 2 < NT) STAGE_B(cur, 0, t + 2); }
            SFENCE();
            BAR();
            SFENCE();
            __builtin_amdgcn_s_setprio(1);
#pragma unroll
            for (int mi = 0; mi < 4; ++mi)
#pragma unroll
                for (int ni = 0; ni < 4; ++ni)
                    acc[mi + 4][ni] = __builtin_amdgcn_mfma_i32_16x16x64_i8(
                        af[mi], bf[ni], acc[mi + 4][ni], 0, 0, 0);
            __builtin_amdgcn_s_setprio(0);
            SFENCE();
            if (ks == 0) {
                if (t < NT - 1) { WAITVM(8); } else { WAITVM(0); }
            } else {
                if (t < NT - 2) { WAITVM(8); }
                else if (t == NT - 2) { WAITVM(4); }
                // t == NT-1: nothing outstanding needed
            }
            SFENCE();
            BAR();
            SFENCE();
        }
    }
#undef STAGE_A
#undef STAGE_B

    // epilogue: C/D layout col = lane&15, row = (lane>>4)*4 + reg; per-row dequant + bias
    float srow[8][4];
#pragma unroll
    for (int mi = 0; mi < 8; ++mi) {
        const int row0 = m0 + wr * 128 + mi * 16 + q * 4;
#pragma unroll
        for (int i = 0; i < 4; ++i) srow[mi][i] = scales[row0 + i];
    }
#pragma unroll
    for (int ni = 0; ni < 4; ++ni) {
        const int col = n0 + wc * 64 + ni * 16 + lr;
        const float bv = bias[col];
#pragma unroll
        for (int mi = 0; mi < 8; ++mi) {
            const int row0 = m0 + wr * 128 + mi * 16 + q * 4;
#pragma unroll
            for (int i = 0; i < 4; ++i)
                C[(size_t)(row0 + i) * N + col] = (float)acc[mi][ni][i] * srow[mi][i] + bv;
        }
    }
}

// ---------------- launch ----------------

extern "C" void kernel_launch(void* const* d_in, const int* in_sizes, int n_in,
                              void* d_out, int out_size, void* d_ws, size_t ws_size,
                              hipStream_t stream) {
    const float* x    = (const float*)d_in[0];  // [8192, 4096]
    const float* w    = (const float*)d_in[1];  // [4096, 4096]
    const float* bias = (const float*)d_in[2];  // [4096]
    float* out        = (float*)d_out;          // [8192, 4096]

    float* scales = (float*)d_ws;                       // 32 KB (8192 f32)
    int8_t* xq = (int8_t*)d_ws + 32768;                 // 32 MB
    int8_t* wq = xq + (size_t)M * K;                    // 16 MB

    // fused: 8192 quant blocks + 16384 binarize blocks, concurrent
    prep<<<M + (N * K / 4) / 256, 256, 0, stream>>>(x, w, xq, scales, wq);

    gemm_i8<<<dim3(512), 512, 0, stream>>>(xq, wq, bias, scales, out);      // 32x16 m,n tiles
}